// Round 7
// baseline (174.706 us; speedup 1.0000x reference)
//
#include <hip/hip_runtime.h>

typedef _Float16 f16;
typedef _Float16 f16x2 __attribute__((ext_vector_type(2)));
typedef _Float16 f16x8 __attribute__((ext_vector_type(8)));
typedef float f32x4 __attribute__((ext_vector_type(4)));

#define I_DIM 320
#define J_DIM 320
#define C_DIM 128
#define NROWS (I_DIM * J_DIM)   // 102400

// ---------------- K0: weight prep (f32 -> f16, MFMA B-fragment order) ------
// layout: [w][ks][n][lane][j]; value = W_w[(ks*32+(lane>>4)*8+j)*128 + n*16+(lane&15)]
__global__ __launch_bounds__(256) void prep_kernel(const float* __restrict__ Wq,
                                                   const float* __restrict__ Wk,
                                                   const float* __restrict__ Wv,
                                                   const float* __restrict__ Wg,
                                                   const float* __restrict__ Wo,
                                                   f16* __restrict__ Wfrag) {
    int f = blockIdx.x * 256 + threadIdx.x;           // < 5*16384
    int j = f & 7, lane = (f >> 3) & 63, n = (f >> 9) & 7;
    int ks = (f >> 12) & 3, w = f >> 14;
    int gq = lane >> 4, r16 = lane & 15;
    const float* W = (w == 0) ? Wq : (w == 1) ? Wk : (w == 2) ? Wv : (w == 3) ? Wg : Wo;
    Wfrag[f] = (f16)W[(size_t)(ks * 32 + gq * 8 + j) * 128 + n * 16 + r16];
}

// ---------------- K1: LayerNorm (f32 -> f16) — unchanged ----------------
__global__ __launch_bounds__(256) void ln_kernel(const float* __restrict__ z,
                                                 const float* __restrict__ scale,
                                                 const float* __restrict__ bias,
                                                 f16* __restrict__ zn) {
    int wave = threadIdx.x >> 6;
    int lane = threadIdx.x & 63;
    int row = blockIdx.x * 4 + wave;
    const float* zr = z + (size_t)row * C_DIM;
    float2 x = *(const float2*)(zr + lane * 2);
    float s = x.x + x.y;
    float sq = x.x * x.x + x.y * x.y;
    #pragma unroll
    for (int o = 32; o; o >>= 1) {
        s  += __shfl_xor(s, o);
        sq += __shfl_xor(sq, o);
    }
    float mu = s * (1.0f / 128.0f);
    float var = sq * (1.0f / 128.0f) - mu * mu;
    float rs = rsqrtf(var + 1e-5f);
    int c0 = lane * 2;
    float y0 = (x.x - mu) * rs * scale[c0] + bias[c0];
    float y1 = (x.y - mu) * rs * scale[c0 + 1] + bias[c0 + 1];
    f16x2 o2 = {(f16)y0, (f16)y1};
    *(f16x2*)(zn + (size_t)row * C_DIM + c0) = o2;
}

// ---------------- K2: fused QKVG-projection + attention per (i,h) ----------
// grid 1280 = i*4+h, 256 threads (4 waves). q/k/v/g never touch HBM.
__global__ __launch_bounds__(256) void attn_mega(const f16* __restrict__ zn,
                                                 const f16* __restrict__ Wfrag,
                                                 const float* __restrict__ bg,
                                                 const int* __restrict__ z_mask,
                                                 f16* __restrict__ gwa) {
    __shared__ f16 Ksh[320][40];     // k-head tile  [key][dh], r1/r5-proven geometry
    __shared__ f16 Vt[32][328];      // v-head tile transposed [dh][key]
    __shared__ float mb[320];
    __shared__ f16 Pb[4][2][16][40]; // per-wave bounce (q + P chunks)

    int h = blockIdx.x & 3;
    int i = blockIdx.x >> 2;
    size_t zbase = (size_t)i * (J_DIM * C_DIM);      // zn row block
    size_t gbase = zbase + h * 32;                   // gwa head slice

    int wave = threadIdx.x >> 6;
    int lane = threadIdx.x & 63;
    int gq = lane >> 4, r16 = lane & 15;

    const f16* wfq = Wfrag;
    const f16* wfk = Wfrag + 16384;
    const f16* wfv = Wfrag + 32768;
    const f16* wfg = Wfrag + 49152;

    // Phase A: mask bias
    for (int t = threadIdx.x; t < 320; t += 256)
        mb[t] = 1e9f * ((float)z_mask[i * J_DIM + t] - 1.0f);

    // Phase B: project K and V head-slices into LDS (wave w: row-tiles w,w+4,..)
    for (int rt = wave; rt < 20; rt += 4) {
        f16x8 a[4];
        #pragma unroll
        for (int ks = 0; ks < 4; ++ks)
            a[ks] = *(const f16x8*)(zn + zbase + (size_t)(rt * 16 + r16) * C_DIM + ks * 32 + gq * 8);
        f32x4 kacc[2] = {}, vacc[2] = {};
        #pragma unroll
        for (int ks = 0; ks < 4; ++ks) {
            #pragma unroll
            for (int n = 0; n < 2; ++n) {
                f16x8 bk = *(const f16x8*)(wfk + (ks * 8 + 2 * h + n) * 512 + lane * 8);
                kacc[n] = __builtin_amdgcn_mfma_f32_16x16x32_f16(a[ks], bk, kacc[n], 0, 0, 0);
                f16x8 bv = *(const f16x8*)(wfv + (ks * 8 + 2 * h + n) * 512 + lane * 8);
                vacc[n] = __builtin_amdgcn_mfma_f32_16x16x32_f16(a[ks], bv, vacc[n], 0, 0, 0);
            }
        }
        // C/D layout: col = n*16+r16, row = rt*16 + gq*4 + rr
        #pragma unroll
        for (int n = 0; n < 2; ++n) {
            #pragma unroll
            for (int rr = 0; rr < 4; ++rr) {
                int key = rt * 16 + gq * 4 + rr;
                int dh = n * 16 + r16;
                Ksh[key][dh] = (f16)kacc[n][rr];
                Vt[dh][key]  = (f16)vacc[n][rr];
            }
        }
    }
    __syncthreads();

    // Phase D: per wave, 5 q-tiles: q-proj + g-proj -> QK^T -> softmax -> PV -> gate
    for (int qt = wave; qt < 20; qt += 4) {
        // q & g projections for rows qt*16 + r16 (A-frags from global zn, L2-hot)
        f16x8 a[4];
        #pragma unroll
        for (int ks = 0; ks < 4; ++ks)
            a[ks] = *(const f16x8*)(zn + zbase + (size_t)(qt * 16 + r16) * C_DIM + ks * 32 + gq * 8);
        f32x4 qacc[2] = {}, gacc[2] = {};
        #pragma unroll
        for (int ks = 0; ks < 4; ++ks) {
            #pragma unroll
            for (int n = 0; n < 2; ++n) {
                f16x8 bq = *(const f16x8*)(wfq + (ks * 8 + 2 * h + n) * 512 + lane * 8);
                qacc[n] = __builtin_amdgcn_mfma_f32_16x16x32_f16(a[ks], bq, qacc[n], 0, 0, 0);
                f16x8 bgf = *(const f16x8*)(wfg + (ks * 8 + 2 * h + n) * 512 + lane * 8);
                gacc[n] = __builtin_amdgcn_mfma_f32_16x16x32_f16(a[ks], bgf, gacc[n], 0, 0, 0);
            }
        }
        // bounce q through per-wave LDS: write C-layout, read A-fragment layout
        #pragma unroll
        for (int n = 0; n < 2; ++n)
            #pragma unroll
            for (int rr = 0; rr < 4; ++rr)
                Pb[wave][0][gq * 4 + rr][n * 16 + r16] = (f16)qacc[n][rr];
        asm volatile("s_waitcnt lgkmcnt(0)" ::: "memory");
        f16x8 qa = *(const f16x8*)(&Pb[wave][0][r16][gq * 8]);

        // QK^T: one MFMA per key-tile (K = dh = 32)
        f32x4 zero = {};
        f32x4 lg[20];
        #pragma unroll
        for (int kt = 0; kt < 20; ++kt) {
            f16x8 kb = *(const f16x8*)(&Ksh[kt * 16 + r16][gq * 8]);
            lg[kt] = __builtin_amdgcn_mfma_f32_16x16x32_f16(qa, kb, zero, 0, 0, 0);
        }
        // softmax over 320 keys, rows jq = qt*16 + gq*4 + r
        float rinv[4];
        #pragma unroll
        for (int r = 0; r < 4; ++r) {
            float mx = -3e38f;
            #pragma unroll
            for (int kt = 0; kt < 20; ++kt) {
                float t = lg[kt][r] + mb[kt * 16 + r16];
                lg[kt][r] = t;
                mx = fmaxf(mx, t);
            }
            #pragma unroll
            for (int o = 1; o < 16; o <<= 1) mx = fmaxf(mx, __shfl_xor(mx, o));
            float s = 0.0f;
            #pragma unroll
            for (int kt = 0; kt < 20; ++kt) {
                float e = __expf(lg[kt][r] - mx);
                lg[kt][r] = e;
                s += e;
            }
            #pragma unroll
            for (int o = 1; o < 16; o <<= 1) s += __shfl_xor(s, o);
            rinv[r] = 1.0f / s;
        }
        // PV via double-buffered LDS bounce for P
        f32x4 wa[2] = {};
        #pragma unroll
        for (int kc = 0; kc < 10; ++kc) {
            int buf = kc & 1;
            #pragma unroll
            for (int t = 0; t < 2; ++t) {
                int kt = kc * 2 + t;
                #pragma unroll
                for (int r = 0; r < 4; ++r)
                    Pb[wave][buf][gq * 4 + r][t * 16 + r16] = (f16)(lg[kt][r] * rinv[r]);
            }
            asm volatile("s_waitcnt lgkmcnt(0)" ::: "memory");
            f16x8 pa = *(const f16x8*)(&Pb[wave][buf][r16][gq * 8]);
            #pragma unroll
            for (int n = 0; n < 2; ++n) {
                f16x8 vb = *(const f16x8*)(&Vt[n * 16 + r16][kc * 32 + gq * 8]);
                wa[n] = __builtin_amdgcn_mfma_f32_16x16x32_f16(pa, vb, wa[n], 0, 0, 0);
            }
        }
        // gate in registers (gacc layout == wa layout) + store head slice
        #pragma unroll
        for (int n = 0; n < 2; ++n) {
            #pragma unroll
            for (int r = 0; r < 4; ++r) {
                int jq = qt * 16 + gq * 4 + r;
                int dh = n * 16 + r16;
                float gv = 1.0f / (1.0f + __expf(-(gacc[n][r] + bg[h * 32 + dh])));
                gwa[gbase + (size_t)jq * C_DIM + dh] = (f16)(gv * wa[n][r]);
            }
        }
    }
}

// ---------------- K4: output projection — unchanged (r4/r5-proven) ---------
__global__ __launch_bounds__(256) void out_kernel(const f16* __restrict__ gwa,
                                                  const f16* __restrict__ Wofrag,
                                                  const float* __restrict__ bo,
                                                  const int* __restrict__ z_mask,
                                                  float* __restrict__ out) {
    int wave = threadIdx.x >> 6;
    int lane = threadIdx.x & 63;
    int gq = lane >> 4, r16 = lane & 15;
    int row0 = blockIdx.x * 256 + wave * 64;

    f32x4 acc[4][8] = {};
    #pragma unroll
    for (int ks = 0; ks < 4; ++ks) {
        f16x8 a[4];
        #pragma unroll
        for (int m = 0; m < 4; ++m)
            a[m] = *(const f16x8*)(gwa + (size_t)(row0 + m * 16 + r16) * C_DIM + ks * 32 + gq * 8);
        #pragma unroll
        for (int n = 0; n < 8; ++n) {
            f16x8 b = *(const f16x8*)(Wofrag + (ks * 8 + n) * 512 + lane * 8);
            #pragma unroll
            for (int m = 0; m < 4; ++m)
                acc[m][n] = __builtin_amdgcn_mfma_f32_16x16x32_f16(a[m], b, acc[m][n], 0, 0, 0);
        }
    }
    #pragma unroll
    for (int m = 0; m < 4; ++m) {
        #pragma unroll
        for (int rr = 0; rr < 4; ++rr) {
            int row = row0 + m * 16 + gq * 4 + rr;
            float mk = (float)z_mask[row];
            #pragma unroll
            for (int n = 0; n < 8; ++n) {
                int col = n * 16 + r16;
                out[(size_t)row * C_DIM + col] = (acc[m][n][rr] + bo[col]) * mk;
            }
        }
    }
}

extern "C" void kernel_launch(void* const* d_in, const int* in_sizes, int n_in,
                              void* d_out, int out_size, void* d_ws, size_t ws_size,
                              hipStream_t stream) {
    const float* z        = (const float*)d_in[0];
    const int*   z_mask   = (const int*)d_in[1];
    const float* ln_scale = (const float*)d_in[2];
    const float* ln_bias  = (const float*)d_in[3];
    const float* Wq       = (const float*)d_in[4];
    const float* Wk       = (const float*)d_in[5];
    const float* Wv       = (const float*)d_in[6];
    const float* Wg       = (const float*)d_in[7];
    const float* bg       = (const float*)d_in[8];
    const float* Wo       = (const float*)d_in[9];
    const float* bo       = (const float*)d_in[10];
    float* out = (float*)d_out;

    char* ws = (char*)d_ws;
    const size_t SZ = (size_t)NROWS * C_DIM * sizeof(f16);  // 26,214,400 B
    f16* zn    = (f16*)(ws);           // live through attn_mega
    f16* gwa   = (f16*)(ws + 1 * SZ);  // separate: zn still read while gwa written
    f16* Wfrag = (f16*)(ws + 2 * SZ);  // 163,840 B

    prep_kernel<<<320, 256, 0, stream>>>(Wq, Wk, Wv, Wg, Wo, Wfrag);
    ln_kernel  <<<NROWS / 4, 256, 0, stream>>>(z, ln_scale, ln_bias, zn);
    attn_mega  <<<I_DIM * 4, 256, 0, stream>>>(zn, Wfrag, bg, z_mask, gwa);
    out_kernel <<<NROWS / 256, 256, 0, stream>>>(gwa, Wfrag + 4 * 16384, bo, z_mask, out);
}

// Round 8
// 149.689 us; speedup vs baseline: 1.1671x; 1.1671x over previous
//
#include <hip/hip_runtime.h>

typedef _Float16 f16;
typedef _Float16 f16x2 __attribute__((ext_vector_type(2)));
typedef _Float16 f16x8 __attribute__((ext_vector_type(8)));
typedef float f32x4 __attribute__((ext_vector_type(4)));

#define I_DIM 320
#define J_DIM 320
#define C_DIM 128
#define NROWS (I_DIM * J_DIM)   // 102400
#define LOG2E 1.44269504f

// ---------------- K0: weight prep (f32 -> f16, MFMA B-fragment order) ------
// layout: [w][ks][n][lane][j]; value = W_w[(ks*32+(lane>>4)*8+j)*128 + n*16+(lane&15)]
__global__ __launch_bounds__(256) void prep_kernel(const float* __restrict__ Wq,
                                                   const float* __restrict__ Wk,
                                                   const float* __restrict__ Wv,
                                                   const float* __restrict__ Wg,
                                                   const float* __restrict__ Wo,
                                                   f16* __restrict__ Wfrag) {
    int f = blockIdx.x * 256 + threadIdx.x;           // < 5*16384
    int j = f & 7, lane = (f >> 3) & 63, n = (f >> 9) & 7;
    int ks = (f >> 12) & 3, w = f >> 14;
    int gq = lane >> 4, r16 = lane & 15;
    const float* W = (w == 0) ? Wq : (w == 1) ? Wk : (w == 2) ? Wv : (w == 3) ? Wg : Wo;
    Wfrag[f] = (f16)W[(size_t)(ks * 32 + gq * 8 + j) * 128 + n * 16 + r16];
}

// ---------------- K1: LayerNorm (f32 -> f16) — unchanged ----------------
__global__ __launch_bounds__(256) void ln_kernel(const float* __restrict__ z,
                                                 const float* __restrict__ scale,
                                                 const float* __restrict__ bias,
                                                 f16* __restrict__ zn) {
    int wave = threadIdx.x >> 6;
    int lane = threadIdx.x & 63;
    int row = blockIdx.x * 4 + wave;
    const float* zr = z + (size_t)row * C_DIM;
    float2 x = *(const float2*)(zr + lane * 2);
    float s = x.x + x.y;
    float sq = x.x * x.x + x.y * x.y;
    #pragma unroll
    for (int o = 32; o; o >>= 1) {
        s  += __shfl_xor(s, o);
        sq += __shfl_xor(sq, o);
    }
    float mu = s * (1.0f / 128.0f);
    float var = sq * (1.0f / 128.0f) - mu * mu;
    float rs = rsqrtf(var + 1e-5f);
    int c0 = lane * 2;
    float y0 = (x.x - mu) * rs * scale[c0] + bias[c0];
    float y1 = (x.y - mu) * rs * scale[c0 + 1] + bias[c0 + 1];
    f16x2 o2 = {(f16)y0, (f16)y1};
    *(f16x2*)(zn + (size_t)row * C_DIM + c0) = o2;
}

// ---------------- K2: fused QKVG-projection + attention per (i,h) ----------
// grid 1280, 256 threads (4 waves). Fused single-pass softmax in exp2 domain
// with offset -12 folded into mbs; 1/sum deferred to epilogue.
__global__ __launch_bounds__(256, 3) void attn_mega(const f16* __restrict__ zn,
                                                    const f16* __restrict__ Wfrag,
                                                    const float* __restrict__ bg,
                                                    const int* __restrict__ z_mask,
                                                    f16* __restrict__ gwa) {
    __shared__ f16 Ksh[320][42];     // 42-f16 stride (21 dw, odd) -> <=2-way banks
    __shared__ f16 Vt[32][330];      // 330-f16 stride (165 dw, odd) -> <=2-way banks
    __shared__ f16 mbs[320];         // LOG2E*maskbias - 12 (masked: -60000)
    __shared__ f16 Pb[4][16][42];    // per-wave bounce (q + P chunks)

    // XCD-bijective swizzle: all 4 heads of an i on one XCD (zn L2 reuse)
    int bid = blockIdx.x;
    int xcd = bid & 7, idx = bid >> 3;
    int i = xcd * 40 + (idx >> 2);
    int h = idx & 3;
    size_t zbase = (size_t)i * (J_DIM * C_DIM);
    size_t gbase = zbase + h * 32;

    int wave = threadIdx.x >> 6;
    int lane = threadIdx.x & 63;
    int gq = lane >> 4, r16 = lane & 15;

    const f16* wfq = Wfrag;
    const f16* wfk = Wfrag + 16384;
    const f16* wfv = Wfrag + 32768;
    const f16* wfg = Wfrag + 49152;

    // Phase A: pre-scaled mask bias (exp2 domain, offset -12 folded in)
    for (int t = threadIdx.x; t < 320; t += 256)
        mbs[t] = (f16)(z_mask[i * J_DIM + t] ? -12.0f : -60000.0f);

    // Phase B: project K and V head-slices into LDS (wave w: row-tiles w,w+4,..)
    for (int rt = wave; rt < 20; rt += 4) {
        f16x8 a[4];
        #pragma unroll
        for (int ks = 0; ks < 4; ++ks)
            a[ks] = *(const f16x8*)(zn + zbase + (size_t)(rt * 16 + r16) * C_DIM + ks * 32 + gq * 8);
        f32x4 kacc[2] = {}, vacc[2] = {};
        #pragma unroll
        for (int ks = 0; ks < 4; ++ks) {
            #pragma unroll
            for (int n = 0; n < 2; ++n) {
                f16x8 bk = *(const f16x8*)(wfk + (ks * 8 + 2 * h + n) * 512 + lane * 8);
                kacc[n] = __builtin_amdgcn_mfma_f32_16x16x32_f16(a[ks], bk, kacc[n], 0, 0, 0);
                f16x8 bv = *(const f16x8*)(wfv + (ks * 8 + 2 * h + n) * 512 + lane * 8);
                vacc[n] = __builtin_amdgcn_mfma_f32_16x16x32_f16(a[ks], bv, vacc[n], 0, 0, 0);
            }
        }
        // C/D layout: col = n*16+r16, row = rt*16 + gq*4 + rr
        #pragma unroll
        for (int n = 0; n < 2; ++n) {
            #pragma unroll
            for (int rr = 0; rr < 4; ++rr) {
                int key = rt * 16 + gq * 4 + rr;
                int dh = n * 16 + r16;
                Ksh[key][dh] = (f16)kacc[n][rr];
                Vt[dh][key]  = (f16)vacc[n][rr];
            }
        }
    }
    __syncthreads();

    // Phase D: per wave, 5 q-tiles: q/g-proj -> fused QK^T+exp2+PV -> gate
    for (int qt = wave; qt < 20; qt += 4) {
        f16x8 a[4];
        #pragma unroll
        for (int ks = 0; ks < 4; ++ks)
            a[ks] = *(const f16x8*)(zn + zbase + (size_t)(qt * 16 + r16) * C_DIM + ks * 32 + gq * 8);
        f32x4 qacc[2] = {}, gacc[2] = {};
        #pragma unroll
        for (int ks = 0; ks < 4; ++ks) {
            #pragma unroll
            for (int n = 0; n < 2; ++n) {
                f16x8 bq = *(const f16x8*)(wfq + (ks * 8 + 2 * h + n) * 512 + lane * 8);
                qacc[n] = __builtin_amdgcn_mfma_f32_16x16x32_f16(a[ks], bq, qacc[n], 0, 0, 0);
                f16x8 bgf = *(const f16x8*)(wfg + (ks * 8 + 2 * h + n) * 512 + lane * 8);
                gacc[n] = __builtin_amdgcn_mfma_f32_16x16x32_f16(a[ks], bgf, gacc[n], 0, 0, 0);
            }
        }
        // bounce q through per-wave LDS: write C-layout, read A-fragment layout
        #pragma unroll
        for (int n = 0; n < 2; ++n)
            #pragma unroll
            for (int rr = 0; rr < 4; ++rr)
                Pb[wave][gq * 4 + rr][n * 16 + r16] = (f16)qacc[n][rr];
        asm volatile("s_waitcnt lgkmcnt(0)" ::: "memory");
        f16x8 qa = *(const f16x8*)(&Pb[wave][r16][gq * 8]);

        f32x4 wa[2] = {};
        float s[4] = {0.0f, 0.0f, 0.0f, 0.0f};
        f32x4 zero = {};
        #pragma unroll
        for (int kc = 0; kc < 10; ++kc) {
            #pragma unroll
            for (int t = 0; t < 2; ++t) {
                int kt = kc * 2 + t;
                f16x8 kb = *(const f16x8*)(&Ksh[kt * 16 + r16][gq * 8]);
                f32x4 sc = __builtin_amdgcn_mfma_f32_16x16x32_f16(qa, kb, zero, 0, 0, 0);
                float mkey = (float)mbs[kt * 16 + r16];
                #pragma unroll
                for (int r = 0; r < 4; ++r) {
                    float p = __builtin_amdgcn_exp2f(fminf(fmaf(sc[r], LOG2E, mkey), 15.0f));
                    s[r] += p;
                    Pb[wave][gq * 4 + r][t * 16 + r16] = (f16)p;
                }
            }
            asm volatile("s_waitcnt lgkmcnt(0)" ::: "memory");
            f16x8 pa = *(const f16x8*)(&Pb[wave][r16][gq * 8]);
            #pragma unroll
            for (int n = 0; n < 2; ++n) {
                f16x8 vb = *(const f16x8*)(&Vt[n * 16 + r16][kc * 32 + gq * 8]);
                wa[n] = __builtin_amdgcn_mfma_f32_16x16x32_f16(pa, vb, wa[n], 0, 0, 0);
            }
        }
        // row-sum reduce (16-lane key groups) -> 1/s
        #pragma unroll
        for (int r = 0; r < 4; ++r) {
            #pragma unroll
            for (int o = 1; o < 16; o <<= 1) s[r] += __shfl_xor(s[r], o);
            s[r] = 1.0f / s[r];
        }
        // gate in registers + normalize + store head slice
        #pragma unroll
        for (int n = 0; n < 2; ++n) {
            #pragma unroll
            for (int r = 0; r < 4; ++r) {
                int jq = qt * 16 + gq * 4 + r;
                int dh = n * 16 + r16;
                float gv = 1.0f / (1.0f + __expf(-(gacc[n][r] + bg[h * 32 + dh])));
                gwa[gbase + (size_t)jq * C_DIM + dh] = (f16)(gv * wa[n][r] * s[r]);
            }
        }
    }
}

// ---------------- K4: output projection — unchanged (r4-r7-proven) ---------
__global__ __launch_bounds__(256) void out_kernel(const f16* __restrict__ gwa,
                                                  const f16* __restrict__ Wofrag,
                                                  const float* __restrict__ bo,
                                                  const int* __restrict__ z_mask,
                                                  float* __restrict__ out) {
    int wave = threadIdx.x >> 6;
    int lane = threadIdx.x & 63;
    int gq = lane >> 4, r16 = lane & 15;
    int row0 = blockIdx.x * 256 + wave * 64;

    f32x4 acc[4][8] = {};
    #pragma unroll
    for (int ks = 0; ks < 4; ++ks) {
        f16x8 a[4];
        #pragma unroll
        for (int m = 0; m < 4; ++m)
            a[m] = *(const f16x8*)(gwa + (size_t)(row0 + m * 16 + r16) * C_DIM + ks * 32 + gq * 8);
        #pragma unroll
        for (int n = 0; n < 8; ++n) {
            f16x8 b = *(const f16x8*)(Wofrag + (ks * 8 + n) * 512 + lane * 8);
            #pragma unroll
            for (int m = 0; m < 4; ++m)
                acc[m][n] = __builtin_amdgcn_mfma_f32_16x16x32_f16(a[m], b, acc[m][n], 0, 0, 0);
        }
    }
    #pragma unroll
    for (int m = 0; m < 4; ++m) {
        #pragma unroll
        for (int rr = 0; rr < 4; ++rr) {
            int row = row0 + m * 16 + gq * 4 + rr;
            float mk = (float)z_mask[row];
            #pragma unroll
            for (int n = 0; n < 8; ++n) {
                int col = n * 16 + r16;
                out[(size_t)row * C_DIM + col] = (acc[m][n][rr] + bo[col]) * mk;
            }
        }
    }
}

extern "C" void kernel_launch(void* const* d_in, const int* in_sizes, int n_in,
                              void* d_out, int out_size, void* d_ws, size_t ws_size,
                              hipStream_t stream) {
    const float* z        = (const float*)d_in[0];
    const int*   z_mask   = (const int*)d_in[1];
    const float* ln_scale = (const float*)d_in[2];
    const float* ln_bias  = (const float*)d_in[3];
    const float* Wq       = (const float*)d_in[4];
    const float* Wk       = (const float*)d_in[5];
    const float* Wv       = (const float*)d_in[6];
    const float* Wg       = (const float*)d_in[7];
    const float* bg       = (const float*)d_in[8];
    const float* Wo       = (const float*)d_in[9];
    const float* bo       = (const float*)d_in[10];
    float* out = (float*)d_out;

    char* ws = (char*)d_ws;
    const size_t SZ = (size_t)NROWS * C_DIM * sizeof(f16);  // 26,214,400 B
    f16* zn    = (f16*)(ws);           // live through attn_mega
    f16* gwa   = (f16*)(ws + 1 * SZ);  // separate: zn still read while gwa written
    f16* Wfrag = (f16*)(ws + 2 * SZ);  // 163,840 B

    prep_kernel<<<320, 256, 0, stream>>>(Wq, Wk, Wv, Wg, Wo, Wfrag);
    ln_kernel  <<<NROWS / 4, 256, 0, stream>>>(z, ln_scale, ln_bias, zn);
    attn_mega  <<<I_DIM * 4, 256, 0, stream>>>(zn, Wfrag, bg, z_mask, gwa);
    out_kernel <<<NROWS / 256, 256, 0, stream>>>(gwa, Wfrag + 4 * 16384, bo, z_mask, out);
}

// Round 9
// 115.411 us; speedup vs baseline: 1.5138x; 1.2970x over previous
//
#include <hip/hip_runtime.h>

typedef _Float16 f16;
typedef _Float16 f16x2 __attribute__((ext_vector_type(2)));
typedef _Float16 f16x4 __attribute__((ext_vector_type(4)));
typedef _Float16 f16x8 __attribute__((ext_vector_type(8)));
typedef float f32x4 __attribute__((ext_vector_type(4)));

#define I_DIM 320
#define J_DIM 320
#define C_DIM 128
#define NROWS (I_DIM * J_DIM)   // 102400
#define LOG2E 1.44269504f

__device__ inline float pk2(float a, float b) {
    f16x2 h = {(f16)a, (f16)b};
    return __builtin_bit_cast(float, h);
}

// ---------------- K0: weight prep (f32 -> f16, MFMA B-fragment order) ------
__global__ __launch_bounds__(256) void prep_kernel(const float* __restrict__ Wq,
                                                   const float* __restrict__ Wk,
                                                   const float* __restrict__ Wv,
                                                   const float* __restrict__ Wg,
                                                   const float* __restrict__ Wo,
                                                   f16* __restrict__ Wfrag) {
    int f = blockIdx.x * 256 + threadIdx.x;           // < 5*16384
    int j = f & 7, lane = (f >> 3) & 63, n = (f >> 9) & 7;
    int ks = (f >> 12) & 3, w = f >> 14;
    int gq = lane >> 4, r16 = lane & 15;
    const float* W = (w == 0) ? Wq : (w == 1) ? Wk : (w == 2) ? Wv : (w == 3) ? Wg : Wo;
    Wfrag[f] = (f16)W[(size_t)(ks * 32 + gq * 8 + j) * 128 + n * 16 + r16];
}

// ---------------- K1: LayerNorm (f32 -> f16) — unchanged ----------------
__global__ __launch_bounds__(256) void ln_kernel(const float* __restrict__ z,
                                                 const float* __restrict__ scale,
                                                 const float* __restrict__ bias,
                                                 f16* __restrict__ zn) {
    int wave = threadIdx.x >> 6;
    int lane = threadIdx.x & 63;
    int row = blockIdx.x * 4 + wave;
    const float* zr = z + (size_t)row * C_DIM;
    float2 x = *(const float2*)(zr + lane * 2);
    float s = x.x + x.y;
    float sq = x.x * x.x + x.y * x.y;
    #pragma unroll
    for (int o = 32; o; o >>= 1) {
        s  += __shfl_xor(s, o);
        sq += __shfl_xor(sq, o);
    }
    float mu = s * (1.0f / 128.0f);
    float var = sq * (1.0f / 128.0f) - mu * mu;
    float rs = rsqrtf(var + 1e-5f);
    int c0 = lane * 2;
    float y0 = (x.x - mu) * rs * scale[c0] + bias[c0];
    float y1 = (x.y - mu) * rs * scale[c0 + 1] + bias[c0 + 1];
    f16x2 o2 = {(f16)y0, (f16)y1};
    *(f16x2*)(zn + (size_t)row * C_DIM + c0) = o2;
}

// ---------------- K2: fused QKVG-projection + attention per (i,h) ----------
// Swapped QK^T (S^T = K·Q^T) so P is redistributed to the PV A-fragment by
// 8 __shfl per 32-key block — no LDS P round-trip. 5 q-tiles per wave share
// each K/V LDS read.
__global__ __launch_bounds__(256, 3) void attn_mega(const f16* __restrict__ zn,
                                                    const f16* __restrict__ Wfrag,
                                                    const float* __restrict__ bg,
                                                    const int* __restrict__ z_mask,
                                                    f16* __restrict__ gwa) {
    __shared__ f16 Ksh[320][40];   // 80B rows: 16B-aligned, bank-uniform b128 reads
    __shared__ f16 Vt[32][328];    // 656B rows: 16B-aligned, bank-uniform b128 reads
    __shared__ f16 mbs[320];
    __shared__ f16 Pb[4][16][40];  // per-wave q-staging bounce

    int bid = blockIdx.x;
    int xcd = bid & 7, idx = bid >> 3;
    int i = xcd * 40 + (idx >> 2);
    int h = idx & 3;
    size_t zbase = (size_t)i * (J_DIM * C_DIM);
    size_t gbase = zbase + h * 32;

    int wave = threadIdx.x >> 6;
    int lane = threadIdx.x & 63;
    int gq = lane >> 4, r16 = lane & 15;

    const f16* wfq = Wfrag;
    const f16* wfk = Wfrag + 16384;
    const f16* wfv = Wfrag + 32768;
    const f16* wfg = Wfrag + 49152;

    for (int t = threadIdx.x; t < 320; t += 256)
        mbs[t] = (f16)(z_mask[i * J_DIM + t] ? -12.0f : -60000.0f);

    // Phase B: project K and V head-slices into LDS
    for (int rt = wave; rt < 20; rt += 4) {
        f16x8 a[4];
        #pragma unroll
        for (int ks = 0; ks < 4; ++ks)
            a[ks] = *(const f16x8*)(zn + zbase + (size_t)(rt * 16 + r16) * C_DIM + ks * 32 + gq * 8);
        f32x4 kacc[2] = {}, vacc[2] = {};
        #pragma unroll
        for (int ks = 0; ks < 4; ++ks) {
            #pragma unroll
            for (int n = 0; n < 2; ++n) {
                f16x8 bk = *(const f16x8*)(wfk + (ks * 8 + 2 * h + n) * 512 + lane * 8);
                kacc[n] = __builtin_amdgcn_mfma_f32_16x16x32_f16(a[ks], bk, kacc[n], 0, 0, 0);
                f16x8 bv = *(const f16x8*)(wfv + (ks * 8 + 2 * h + n) * 512 + lane * 8);
                vacc[n] = __builtin_amdgcn_mfma_f32_16x16x32_f16(a[ks], bv, vacc[n], 0, 0, 0);
            }
        }
        #pragma unroll
        for (int n = 0; n < 2; ++n) {
            #pragma unroll
            for (int rr = 0; rr < 4; ++rr)
                Ksh[rt * 16 + gq * 4 + rr][n * 16 + r16] = (f16)kacc[n][rr];
            f16x4 vp = {(f16)vacc[n][0], (f16)vacc[n][1], (f16)vacc[n][2], (f16)vacc[n][3]};
            *(f16x4*)(&Vt[n * 16 + r16][rt * 16 + gq * 4]) = vp;
        }
    }
    __syncthreads();

    // Phase C: stage Q A/B-fragments for this wave's 5 q-tiles (LDS bounce)
    f16x8 qa[5];
    #pragma unroll
    for (int u = 0; u < 5; ++u) {
        int qt = u * 4 + wave;
        f16x8 a[4];
        #pragma unroll
        for (int ks = 0; ks < 4; ++ks)
            a[ks] = *(const f16x8*)(zn + zbase + (size_t)(qt * 16 + r16) * C_DIM + ks * 32 + gq * 8);
        f32x4 qacc[2] = {};
        #pragma unroll
        for (int ks = 0; ks < 4; ++ks) {
            #pragma unroll
            for (int n = 0; n < 2; ++n) {
                f16x8 bq = *(const f16x8*)(wfq + (ks * 8 + 2 * h + n) * 512 + lane * 8);
                qacc[n] = __builtin_amdgcn_mfma_f32_16x16x32_f16(a[ks], bq, qacc[n], 0, 0, 0);
            }
        }
        #pragma unroll
        for (int n = 0; n < 2; ++n)
            #pragma unroll
            for (int rr = 0; rr < 4; ++rr)
                Pb[wave][gq * 4 + rr][n * 16 + r16] = (f16)qacc[n][rr];
        asm volatile("s_waitcnt lgkmcnt(0)" ::: "memory");
        qa[u] = *(const f16x8*)(&Pb[wave][r16][gq * 8]);
    }

    // Phase D: main K loop — 32 keys/iter, all 5 q-tiles share each read
    int aA = ((2 * gq) & 3) * 16 + r16;       // shfl src for slots j=0..3
    int aB = ((2 * gq + 1) & 3) * 16 + r16;   // shfl src for slots j=4..7
    bool tsel = (gq >= 2);                    // tile select: keys 16-31 of block
    const f32x4 zero = {};
    f32x4 wa[5][2] = {};
    float s[5] = {0.f, 0.f, 0.f, 0.f, 0.f};

    for (int kc = 0; kc < 10; ++kc) {
        f16x8 kb0 = *(const f16x8*)(&Ksh[kc * 32 + r16][gq * 8]);
        f16x8 kb1 = *(const f16x8*)(&Ksh[kc * 32 + 16 + r16][gq * 8]);
        f16x4 mk0 = *(const f16x4*)(&mbs[kc * 32 + 4 * gq]);
        f16x4 mk1 = *(const f16x4*)(&mbs[kc * 32 + 16 + 4 * gq]);
        f16x8 vb0 = *(const f16x8*)(&Vt[r16][kc * 32 + gq * 8]);
        f16x8 vb1 = *(const f16x8*)(&Vt[16 + r16][kc * 32 + gq * 8]);
        #pragma unroll
        for (int u = 0; u < 5; ++u) {
            // S^T: lane holds S[q=r16][key = kc*32 (+16·t) + 4·gq + r]
            f32x4 sc0 = __builtin_amdgcn_mfma_f32_16x16x32_f16(kb0, qa[u], zero, 0, 0, 0);
            f32x4 sc1 = __builtin_amdgcn_mfma_f32_16x16x32_f16(kb1, qa[u], zero, 0, 0, 0);
            float p0[4], p1[4];
            #pragma unroll
            for (int r = 0; r < 4; ++r) {
                p0[r] = __builtin_amdgcn_exp2f(fminf(fmaf(sc0[r], LOG2E, (float)mk0[r]), 15.0f));
                p1[r] = __builtin_amdgcn_exp2f(fminf(fmaf(sc1[r], LOG2E, (float)mk1[r]), 15.0f));
                s[u] += p0[r] + p1[r];
            }
            float pk00 = pk2(p0[0], p0[1]), pk01 = pk2(p0[2], p0[3]);
            float pk10 = pk2(p1[0], p1[1]), pk11 = pk2(p1[2], p1[3]);
            // redistribute P into the PV A-fragment (pure cross-lane, no LDS)
            float x0 = __shfl(pk00, aA), x1 = __shfl(pk01, aA);
            float x2 = __shfl(pk00, aB), x3 = __shfl(pk01, aB);
            float y0 = __shfl(pk10, aA), y1 = __shfl(pk11, aA);
            float y2 = __shfl(pk10, aB), y3 = __shfl(pk11, aB);
            union { float f[4]; f16x8 v; } pu;
            pu.f[0] = tsel ? y0 : x0;
            pu.f[1] = tsel ? y1 : x1;
            pu.f[2] = tsel ? y2 : x2;
            pu.f[3] = tsel ? y3 : x3;
            wa[u][0] = __builtin_amdgcn_mfma_f32_16x16x32_f16(pu.v, vb0, wa[u][0], 0, 0, 0);
            wa[u][1] = __builtin_amdgcn_mfma_f32_16x16x32_f16(pu.v, vb1, wa[u][1], 0, 0, 0);
        }
    }

    // Epilogue: row-sum finish, deferred g-projection, gate, store
    float bgv0 = bg[h * 32 + r16];
    float bgv1 = bg[h * 32 + 16 + r16];
    #pragma unroll
    for (int u = 0; u < 5; ++u) {
        int qt = u * 4 + wave;
        float su = s[u];
        su += __shfl_xor(su, 16);
        su += __shfl_xor(su, 32);           // su = full sum for q = r16
        float rinv[4];
        #pragma unroll
        for (int r = 0; r < 4; ++r)
            rinv[r] = 1.0f / __shfl(su, gq * 4 + r);
        f16x8 a[4];
        #pragma unroll
        for (int ks = 0; ks < 4; ++ks)
            a[ks] = *(const f16x8*)(zn + zbase + (size_t)(qt * 16 + r16) * C_DIM + ks * 32 + gq * 8);
        f32x4 gacc[2] = {};
        #pragma unroll
        for (int ks = 0; ks < 4; ++ks) {
            #pragma unroll
            for (int n = 0; n < 2; ++n) {
                f16x8 bgf = *(const f16x8*)(wfg + (ks * 8 + 2 * h + n) * 512 + lane * 8);
                gacc[n] = __builtin_amdgcn_mfma_f32_16x16x32_f16(a[ks], bgf, gacc[n], 0, 0, 0);
            }
        }
        #pragma unroll
        for (int n = 0; n < 2; ++n) {
            float bgn = n ? bgv1 : bgv0;
            #pragma unroll
            for (int r = 0; r < 4; ++r) {
                int jq = qt * 16 + gq * 4 + r;
                int dh = n * 16 + r16;
                float gv = 1.0f / (1.0f + __expf(-(gacc[n][r] + bgn)));
                gwa[gbase + (size_t)jq * C_DIM + dh] = (f16)(gv * wa[u][n][r] * rinv[r]);
            }
        }
    }
}

// ---------------- K4: output projection — unchanged (r4-r8-proven) ---------
__global__ __launch_bounds__(256) void out_kernel(const f16* __restrict__ gwa,
                                                  const f16* __restrict__ Wofrag,
                                                  const float* __restrict__ bo,
                                                  const int* __restrict__ z_mask,
                                                  float* __restrict__ out) {
    int wave = threadIdx.x >> 6;
    int lane = threadIdx.x & 63;
    int gq = lane >> 4, r16 = lane & 15;
    int row0 = blockIdx.x * 256 + wave * 64;

    f32x4 acc[4][8] = {};
    #pragma unroll
    for (int ks = 0; ks < 4; ++ks) {
        f16x8 a[4];
        #pragma unroll
        for (int m = 0; m < 4; ++m)
            a[m] = *(const f16x8*)(gwa + (size_t)(row0 + m * 16 + r16) * C_DIM + ks * 32 + gq * 8);
        #pragma unroll
        for (int n = 0; n < 8; ++n) {
            f16x8 b = *(const f16x8*)(Wofrag + (ks * 8 + n) * 512 + lane * 8);
            #pragma unroll
            for (int m = 0; m < 4; ++m)
                acc[m][n] = __builtin_amdgcn_mfma_f32_16x16x32_f16(a[m], b, acc[m][n], 0, 0, 0);
        }
    }
    #pragma unroll
    for (int m = 0; m < 4; ++m) {
        #pragma unroll
        for (int rr = 0; rr < 4; ++rr) {
            int row = row0 + m * 16 + gq * 4 + rr;
            float mk = (float)z_mask[row];
            #pragma unroll
            for (int n = 0; n < 8; ++n) {
                int col = n * 16 + r16;
                out[(size_t)row * C_DIM + col] = (acc[m][n][rr] + bo[col]) * mk;
            }
        }
    }
}

extern "C" void kernel_launch(void* const* d_in, const int* in_sizes, int n_in,
                              void* d_out, int out_size, void* d_ws, size_t ws_size,
                              hipStream_t stream) {
    const float* z        = (const float*)d_in[0];
    const int*   z_mask   = (const int*)d_in[1];
    const float* ln_scale = (const float*)d_in[2];
    const float* ln_bias  = (const float*)d_in[3];
    const float* Wq       = (const float*)d_in[4];
    const float* Wk       = (const float*)d_in[5];
    const float* Wv       = (const float*)d_in[6];
    const float* Wg       = (const float*)d_in[7];
    const float* bg       = (const float*)d_in[8];
    const float* Wo       = (const float*)d_in[9];
    const float* bo       = (const float*)d_in[10];
    float* out = (float*)d_out;

    char* ws = (char*)d_ws;
    const size_t SZ = (size_t)NROWS * C_DIM * sizeof(f16);  // 26,214,400 B
    f16* zn    = (f16*)(ws);           // live through attn_mega
    f16* gwa   = (f16*)(ws + 1 * SZ);  // separate: zn still read while gwa written
    f16* Wfrag = (f16*)(ws + 2 * SZ);  // 163,840 B

    prep_kernel<<<320, 256, 0, stream>>>(Wq, Wk, Wv, Wg, Wo, Wfrag);
    ln_kernel  <<<NROWS / 4, 256, 0, stream>>>(z, ln_scale, ln_bias, zn);
    attn_mega  <<<I_DIM * 4, 256, 0, stream>>>(zn, Wfrag, bg, z_mask, gwa);
    out_kernel <<<NROWS / 256, 256, 0, stream>>>(gwa, Wfrag + 4 * 16384, bo, z_mask, out);
}

// Round 11
// 109.083 us; speedup vs baseline: 1.6016x; 1.0580x over previous
//
#include <hip/hip_runtime.h>

typedef _Float16 f16;
typedef _Float16 f16x2 __attribute__((ext_vector_type(2)));
typedef _Float16 f16x4 __attribute__((ext_vector_type(4)));
typedef _Float16 f16x8 __attribute__((ext_vector_type(8)));
typedef float f32x4 __attribute__((ext_vector_type(4)));

#define I_DIM 320
#define J_DIM 320
#define C_DIM 128
#define NROWS (I_DIM * J_DIM)   // 102400
#define LOG2E 1.44269504f

__device__ inline float pkrtz(float a, float b) {
    return __builtin_bit_cast(float, __builtin_amdgcn_cvt_pkrtz(a, b));  // v_cvt_pkrtz_f16_f32
}

// ---------------- K0: weight prep (f32 -> f16, MFMA B-fragment order) ------
__global__ __launch_bounds__(256) void prep_kernel(const float* __restrict__ Wq,
                                                   const float* __restrict__ Wk,
                                                   const float* __restrict__ Wv,
                                                   const float* __restrict__ Wg,
                                                   const float* __restrict__ Wo,
                                                   f16* __restrict__ Wfrag) {
    int f = blockIdx.x * 256 + threadIdx.x;           // < 5*16384
    int j = f & 7, lane = (f >> 3) & 63, n = (f >> 9) & 7;
    int ks = (f >> 12) & 3, w = f >> 14;
    int gq = lane >> 4, r16 = lane & 15;
    const float* W = (w == 0) ? Wq : (w == 1) ? Wk : (w == 2) ? Wv : (w == 3) ? Wg : Wo;
    Wfrag[f] = (f16)W[(size_t)(ks * 32 + gq * 8 + j) * 128 + n * 16 + r16];
}

// ---------------- K1: LayerNorm (f32 -> f16) — unchanged ----------------
__global__ __launch_bounds__(256) void ln_kernel(const float* __restrict__ z,
                                                 const float* __restrict__ scale,
                                                 const float* __restrict__ bias,
                                                 f16* __restrict__ zn) {
    int wave = threadIdx.x >> 6;
    int lane = threadIdx.x & 63;
    int row = blockIdx.x * 4 + wave;
    const float* zr = z + (size_t)row * C_DIM;
    float2 x = *(const float2*)(zr + lane * 2);
    float s = x.x + x.y;
    float sq = x.x * x.x + x.y * x.y;
    #pragma unroll
    for (int o = 32; o; o >>= 1) {
        s  += __shfl_xor(s, o);
        sq += __shfl_xor(sq, o);
    }
    float mu = s * (1.0f / 128.0f);
    float var = sq * (1.0f / 128.0f) - mu * mu;
    float rs = rsqrtf(var + 1e-5f);
    int c0 = lane * 2;
    float y0 = (x.x - mu) * rs * scale[c0] + bias[c0];
    float y1 = (x.y - mu) * rs * scale[c0 + 1] + bias[c0 + 1];
    f16x2 o2 = {(f16)y0, (f16)y1};
    *(f16x2*)(zn + (size_t)row * C_DIM + c0) = o2;
}

// ---------------- K2: fused QKVG-projection + attention per (i,h) ----------
// Swapped QK^T (S^T = K·Q^T) + sigma-relabeled V^T columns so the PV
// A-fragment is fully LANE-LOCAL: no shuffles, no LDS P round-trip.
// V^T column tau(8g+j) = (j>=4)*16 + 4g + (j&3) within each 32-key block.
__global__ __launch_bounds__(256, 3) void attn_mega(const f16* __restrict__ zn,
                                                    const f16* __restrict__ Wfrag,
                                                    const float* __restrict__ bg,
                                                    const int* __restrict__ z_mask,
                                                    f16* __restrict__ gwa) {
    __shared__ f16 Ksh[320][40];   // 80B rows: 16B-aligned
    __shared__ f16 Vt[32][328];    // 656B rows: 16B-aligned, sigma-ordered cols
    __shared__ f16 mbs[320];
    __shared__ f16 Pb[4][16][40];  // per-wave q-staging bounce

    int bid = blockIdx.x;
    int xcd = bid & 7, idx = bid >> 3;
    int i = xcd * 40 + (idx >> 2);
    int h = idx & 3;
    size_t zbase = (size_t)i * (J_DIM * C_DIM);
    size_t gbase = zbase + h * 32;

    int wave = threadIdx.x >> 6;
    int lane = threadIdx.x & 63;
    int gq = lane >> 4, r16 = lane & 15;

    const f16* wfq = Wfrag;
    const f16* wfk = Wfrag + 16384;
    const f16* wfv = Wfrag + 32768;
    const f16* wfg = Wfrag + 49152;

    for (int t = threadIdx.x; t < 320; t += 256)
        mbs[t] = (f16)(z_mask[i * J_DIM + t] ? -12.0f : -60000.0f);

    // Phase B: project K and V head-slices into LDS
    for (int rt = wave; rt < 20; rt += 4) {
        f16x8 a[4];
        #pragma unroll
        for (int ks = 0; ks < 4; ++ks)
            a[ks] = *(const f16x8*)(zn + zbase + (size_t)(rt * 16 + r16) * C_DIM + ks * 32 + gq * 8);
        f32x4 kacc[2] = {}, vacc[2] = {};
        #pragma unroll
        for (int ks = 0; ks < 4; ++ks) {
            #pragma unroll
            for (int n = 0; n < 2; ++n) {
                f16x8 bk = *(const f16x8*)(wfk + (ks * 8 + 2 * h + n) * 512 + lane * 8);
                kacc[n] = __builtin_amdgcn_mfma_f32_16x16x32_f16(a[ks], bk, kacc[n], 0, 0, 0);
                f16x8 bv = *(const f16x8*)(wfv + (ks * 8 + 2 * h + n) * 512 + lane * 8);
                vacc[n] = __builtin_amdgcn_mfma_f32_16x16x32_f16(a[ks], bv, vacc[n], 0, 0, 0);
            }
        }
        // K: natural order. V^T: sigma-relabeled column base
        int colbase = (rt >> 1) * 32 + gq * 8 + (rt & 1) * 4;
        #pragma unroll
        for (int n = 0; n < 2; ++n) {
            #pragma unroll
            for (int rr = 0; rr < 4; ++rr)
                Ksh[rt * 16 + gq * 4 + rr][n * 16 + r16] = (f16)kacc[n][rr];
            f16x4 vp = {(f16)vacc[n][0], (f16)vacc[n][1], (f16)vacc[n][2], (f16)vacc[n][3]};
            *(f16x4*)(&Vt[n * 16 + r16][colbase]) = vp;
        }
    }
    __syncthreads();

    // Phase C: stage Q B-fragments for this wave's 5 q-tiles (LDS bounce)
    f16x8 qa[5];
    #pragma unroll
    for (int u = 0; u < 5; ++u) {
        int qt = u * 4 + wave;
        f16x8 a[4];
        #pragma unroll
        for (int ks = 0; ks < 4; ++ks)
            a[ks] = *(const f16x8*)(zn + zbase + (size_t)(qt * 16 + r16) * C_DIM + ks * 32 + gq * 8);
        f32x4 qacc[2] = {};
        #pragma unroll
        for (int ks = 0; ks < 4; ++ks) {
            #pragma unroll
            for (int n = 0; n < 2; ++n) {
                f16x8 bq = *(const f16x8*)(wfq + (ks * 8 + 2 * h + n) * 512 + lane * 8);
                qacc[n] = __builtin_amdgcn_mfma_f32_16x16x32_f16(a[ks], bq, qacc[n], 0, 0, 0);
            }
        }
        #pragma unroll
        for (int n = 0; n < 2; ++n)
            #pragma unroll
            for (int rr = 0; rr < 4; ++rr)
                Pb[wave][gq * 4 + rr][n * 16 + r16] = (f16)qacc[n][rr];
        asm volatile("s_waitcnt lgkmcnt(0)" ::: "memory");
        qa[u] = *(const f16x8*)(&Pb[wave][r16][gq * 8]);
    }

    // Phase D: main K loop — 32 keys/iter, all 5 q-tiles share each read.
    // P -> PV A-fragment is lane-local: slots 0-3 = packed sc0, 4-7 = sc1.
    const f32x4 zero = {};
    f32x4 wa[5][2] = {};
    float s[5] = {0.f, 0.f, 0.f, 0.f, 0.f};

    for (int kc = 0; kc < 10; ++kc) {
        f16x8 kb0 = *(const f16x8*)(&Ksh[kc * 32 + r16][gq * 8]);
        f16x8 kb1 = *(const f16x8*)(&Ksh[kc * 32 + 16 + r16][gq * 8]);
        f16x4 mk0 = *(const f16x4*)(&mbs[kc * 32 + 4 * gq]);
        f16x4 mk1 = *(const f16x4*)(&mbs[kc * 32 + 16 + 4 * gq]);
        f16x8 vb0 = *(const f16x8*)(&Vt[r16][kc * 32 + gq * 8]);
        f16x8 vb1 = *(const f16x8*)(&Vt[16 + r16][kc * 32 + gq * 8]);
        #pragma unroll
        for (int u = 0; u < 5; ++u) {
            // S^T: lane holds S[key = kc*32 (+16) + 4*gq + r][q = r16]
            f32x4 sc0 = __builtin_amdgcn_mfma_f32_16x16x32_f16(kb0, qa[u], zero, 0, 0, 0);
            f32x4 sc1 = __builtin_amdgcn_mfma_f32_16x16x32_f16(kb1, qa[u], zero, 0, 0, 0);
            float p0[4], p1[4];
            #pragma unroll
            for (int r = 0; r < 4; ++r) {
                p0[r] = __builtin_amdgcn_exp2f(fminf(fmaf(sc0[r], LOG2E, (float)mk0[r]), 15.0f));
                p1[r] = __builtin_amdgcn_exp2f(fminf(fmaf(sc1[r], LOG2E, (float)mk1[r]), 15.0f));
                s[u] += p0[r] + p1[r];
            }
            union { float f[4]; f16x8 v; } pu;
            pu.f[0] = pkrtz(p0[0], p0[1]);
            pu.f[1] = pkrtz(p0[2], p0[3]);
            pu.f[2] = pkrtz(p1[0], p1[1]);
            pu.f[3] = pkrtz(p1[2], p1[3]);
            wa[u][0] = __builtin_amdgcn_mfma_f32_16x16x32_f16(pu.v, vb0, wa[u][0], 0, 0, 0);
            wa[u][1] = __builtin_amdgcn_mfma_f32_16x16x32_f16(pu.v, vb1, wa[u][1], 0, 0, 0);
        }
    }

    // Epilogue: row-sum finish, deferred g-projection, gate, store
    float bgv0 = bg[h * 32 + r16];
    float bgv1 = bg[h * 32 + 16 + r16];
    #pragma unroll
    for (int u = 0; u < 5; ++u) {
        int qt = u * 4 + wave;
        float su = s[u];
        su += __shfl_xor(su, 16);
        su += __shfl_xor(su, 32);           // su = full sum for q = r16
        float rinv[4];
        #pragma unroll
        for (int r = 0; r < 4; ++r)
            rinv[r] = 1.0f / __shfl(su, gq * 4 + r);
        f16x8 a[4];
        #pragma unroll
        for (int ks = 0; ks < 4; ++ks)
            a[ks] = *(const f16x8*)(zn + zbase + (size_t)(qt * 16 + r16) * C_DIM + ks * 32 + gq * 8);
        f32x4 gacc[2] = {};
        #pragma unroll
        for (int ks = 0; ks < 4; ++ks) {
            #pragma unroll
            for (int n = 0; n < 2; ++n) {
                f16x8 bgf = *(const f16x8*)(wfg + (ks * 8 + 2 * h + n) * 512 + lane * 8);
                gacc[n] = __builtin_amdgcn_mfma_f32_16x16x32_f16(a[ks], bgf, gacc[n], 0, 0, 0);
            }
        }
        #pragma unroll
        for (int n = 0; n < 2; ++n) {
            float bgn = n ? bgv1 : bgv0;
            #pragma unroll
            for (int r = 0; r < 4; ++r) {
                int jq = qt * 16 + gq * 4 + r;
                int dh = n * 16 + r16;
                float gv = 1.0f / (1.0f + __expf(-(gacc[n][r] + bgn)));
                gwa[gbase + (size_t)jq * C_DIM + dh] = (f16)(gv * wa[u][n][r] * rinv[r]);
            }
        }
    }
}

// ---------------- K4: output projection — unchanged (r4-r9-proven) ---------
__global__ __launch_bounds__(256) void out_kernel(const f16* __restrict__ gwa,
                                                  const f16* __restrict__ Wofrag,
                                                  const float* __restrict__ bo,
                                                  const int* __restrict__ z_mask,
                                                  float* __restrict__ out) {
    int wave = threadIdx.x >> 6;
    int lane = threadIdx.x & 63;
    int gq = lane >> 4, r16 = lane & 15;
    int row0 = blockIdx.x * 256 + wave * 64;

    f32x4 acc[4][8] = {};
    #pragma unroll
    for (int ks = 0; ks < 4; ++ks) {
        f16x8 a[4];
        #pragma unroll
        for (int m = 0; m < 4; ++m)
            a[m] = *(const f16x8*)(gwa + (size_t)(row0 + m * 16 + r16) * C_DIM + ks * 32 + gq * 8);
        #pragma unroll
        for (int n = 0; n < 8; ++n) {
            f16x8 b = *(const f16x8*)(Wofrag + (ks * 8 + n) * 512 + lane * 8);
            #pragma unroll
            for (int m = 0; m < 4; ++m)
                acc[m][n] = __builtin_amdgcn_mfma_f32_16x16x32_f16(a[m], b, acc[m][n], 0, 0, 0);
        }
    }
    #pragma unroll
    for (int m = 0; m < 4; ++m) {
        #pragma unroll
        for (int rr = 0; rr < 4; ++rr) {
            int row = row0 + m * 16 + gq * 4 + rr;
            float mk = (float)z_mask[row];
            #pragma unroll
            for (int n = 0; n < 8; ++n) {
                int col = n * 16 + r16;
                out[(size_t)row * C_DIM + col] = (acc[m][n][rr] + bo[col]) * mk;
            }
        }
    }
}

extern "C" void kernel_launch(void* const* d_in, const int* in_sizes, int n_in,
                              void* d_out, int out_size, void* d_ws, size_t ws_size,
                              hipStream_t stream) {
    const float* z        = (const float*)d_in[0];
    const int*   z_mask   = (const int*)d_in[1];
    const float* ln_scale = (const float*)d_in[2];
    const float* ln_bias  = (const float*)d_in[3];
    const float* Wq       = (const float*)d_in[4];
    const float* Wk       = (const float*)d_in[5];
    const float* Wv       = (const float*)d_in[6];
    const float* Wg       = (const float*)d_in[7];
    const float* bg       = (const float*)d_in[8];
    const float* Wo       = (const float*)d_in[9];
    const float* bo       = (const float*)d_in[10];
    float* out = (float*)d_out;

    char* ws = (char*)d_ws;
    const size_t SZ = (size_t)NROWS * C_DIM * sizeof(f16);  // 26,214,400 B
    f16* zn    = (f16*)(ws);           // live through attn_mega
    f16* gwa   = (f16*)(ws + 1 * SZ);  // separate: zn still read while gwa written
    f16* Wfrag = (f16*)(ws + 2 * SZ);  // 163,840 B

    prep_kernel<<<320, 256, 0, stream>>>(Wq, Wk, Wv, Wg, Wo, Wfrag);
    ln_kernel  <<<NROWS / 4, 256, 0, stream>>>(z, ln_scale, ln_bias, zn);
    attn_mega  <<<I_DIM * 4, 256, 0, stream>>>(zn, Wfrag, bg, z_mask, gwa);
    out_kernel <<<NROWS / 256, 256, 0, stream>>>(gwa, Wfrag + 4 * 16384, bo, z_mask, out);
}